// Round 3
// baseline (1797.646 us; speedup 1.0000x reference)
//
#include <hip/hip_runtime.h>
#include <hip/hip_bf16.h>

typedef unsigned short u16;
typedef unsigned int   u32;
typedef __attribute__((ext_vector_type(8))) unsigned short u16x8;
typedef __attribute__((ext_vector_type(4))) unsigned short u16x4;

#define BATCH 4
#define CH 512
#define NN 4096
#define CQ 64

__device__ __forceinline__ float bf2f(u16 v) {
    union { unsigned int u; float f; } x; x.u = ((unsigned int)v) << 16; return x.f;
}
__device__ __forceinline__ u16 f2bf(float f) {
    union { float fv; unsigned int u; } x; x.fv = f;
    unsigned int r = x.u + 0x7FFFu + ((x.u >> 16) & 1u);  // round-to-nearest-even
    return (u16)(r >> 16);
}

// ---------------------------------------------------------------------------
// Input dtype detector (safety net): fp32 N(0,1) exponent fields land in
// [100,132] essentially always; other interpretations don't. flag: 0=fp32, 1=bf16.
// ---------------------------------------------------------------------------
__global__ __launch_bounds__(64) void detect_kernel(const u32* __restrict__ xw,
                                                    int* __restrict__ flag)
{
    const u32 w  = xw[threadIdx.x];
    const u32 ex = (w >> 23) & 0xFFu;
    const int plausible = (ex >= 100u && ex <= 132u) ? 1 : 0;
    const unsigned long long m = __ballot(plausible);
    if (threadIdx.x == 0) flag[0] = (__popcll(m) >= 48) ? 0 : 1;
}

// ---------------------------------------------------------------------------
// Projection GEMM: Out[o][n] = sum_c W[o][c] * x[b][c][n], o in [0,640)
//   o <  64 : Wq row o      -> fT[b][n][o]      (fp32, transposed)
//   o < 128 : Wk row o-64   -> gT[b][n][o-64]   (fp32, transposed)
//   else    : Wv row o-128  -> hv[b][o-128][n]  (bf16)
// BM=BN=BK=64, 256 threads, 4x4 micro-tile, fp32 LDS tiles.
// ---------------------------------------------------------------------------
__global__ __launch_bounds__(256) void proj_kernel(
    const void* __restrict__ xin, const void* __restrict__ Wq,
    const void* __restrict__ Wk, const void* __restrict__ Wv,
    const int* __restrict__ flag,
    float* __restrict__ fT, float* __restrict__ gT, u16* __restrict__ hv)
{
    const int isbf = *flag;
    const int nb = blockIdx.x;   // 64 col-blocks
    const int rb = blockIdx.y;   // 10 row-blocks (640 output rows)
    const int b  = blockIdx.z;
    const int n0 = nb * 64, o0 = rb * 64;
    const int t  = threadIdx.x;
    const int ty = t >> 4, tx = t & 15;

    __shared__ float Wl[64][68];  // [k][o] transposed
    __shared__ float Xl[64][68];  // [k][n]

    float acc[4][4];
#pragma unroll
    for (int r = 0; r < 4; ++r)
#pragma unroll
        for (int q = 0; q < 4; ++q) acc[r][q] = 0.f;

    // staging decomposition: linear index li = rep*256 + t covers the 64x64 tile
    // W side uses (row-within-tile = so, k-offset = sk) like round 2 (verified):
    const int so = t >> 2;           // 0..63
    const int sk = (t & 3) * 16;     // 0,16,32,48

    const void* wsrc; int wrow;
    {
        const int go = o0 + so;
        if (go < 64)       { wsrc = Wq; wrow = go; }
        else if (go < 128) { wsrc = Wk; wrow = go - 64; }
        else               { wsrc = Wv; wrow = go - 128; }
    }

    for (int k0 = 0; k0 < CH; k0 += 64) {
        if (isbf) {   // -------- bf16 input path --------
            {
                const u16* p = (const u16*)wsrc + (size_t)wrow * CH + k0 + sk;
                const u16x8 w0 = *(const u16x8*)p;
                const u16x8 w1 = *(const u16x8*)(p + 8);
#pragma unroll
                for (int e = 0; e < 8; ++e) Wl[sk + e][so] = bf2f(w0[e]);
#pragma unroll
                for (int e = 0; e < 8; ++e) Wl[sk + 8 + e][so] = bf2f(w1[e]);
            }
            {
                const u16* p = (const u16*)xin +
                               ((size_t)(b * CH + k0 + so)) * NN + n0 + sk;
                const u16x8 x0 = *(const u16x8*)p;
                const u16x8 x1 = *(const u16x8*)(p + 8);
                *(float4*)&Xl[so][sk] =
                    make_float4(bf2f(x0[0]), bf2f(x0[1]), bf2f(x0[2]), bf2f(x0[3]));
                *(float4*)&Xl[so][sk + 4] =
                    make_float4(bf2f(x0[4]), bf2f(x0[5]), bf2f(x0[6]), bf2f(x0[7]));
                *(float4*)&Xl[so][sk + 8] =
                    make_float4(bf2f(x1[0]), bf2f(x1[1]), bf2f(x1[2]), bf2f(x1[3]));
                *(float4*)&Xl[so][sk + 12] =
                    make_float4(bf2f(x1[4]), bf2f(x1[5]), bf2f(x1[6]), bf2f(x1[7]));
            }
        } else {      // -------- fp32 input path --------
            {
                const float* p = (const float*)wsrc + (size_t)wrow * CH + k0 + sk;
                const float4 a0 = ((const float4*)p)[0];
                const float4 a1 = ((const float4*)p)[1];
                const float4 a2 = ((const float4*)p)[2];
                const float4 a3 = ((const float4*)p)[3];
                const float av[16] = {a0.x,a0.y,a0.z,a0.w, a1.x,a1.y,a1.z,a1.w,
                                      a2.x,a2.y,a2.z,a2.w, a3.x,a3.y,a3.z,a3.w};
#pragma unroll
                for (int e = 0; e < 16; ++e) Wl[sk + e][so] = av[e];
            }
            {
                const float* p = (const float*)xin +
                                 ((size_t)(b * CH + k0 + so)) * NN + n0 + sk;
                *(float4*)&Xl[so][sk]      = ((const float4*)p)[0];
                *(float4*)&Xl[so][sk + 4]  = ((const float4*)p)[1];
                *(float4*)&Xl[so][sk + 8]  = ((const float4*)p)[2];
                *(float4*)&Xl[so][sk + 12] = ((const float4*)p)[3];
            }
        }
        __syncthreads();
#pragma unroll 16
        for (int kk = 0; kk < 64; ++kk) {
            const float4 a  = *(const float4*)&Wl[kk][ty * 4];
            const float4 bv = *(const float4*)&Xl[kk][tx * 4];
            const float av[4] = {a.x, a.y, a.z, a.w};
            const float bb[4] = {bv.x, bv.y, bv.z, bv.w};
#pragma unroll
            for (int r = 0; r < 4; ++r)
#pragma unroll
                for (int q = 0; q < 4; ++q) acc[r][q] += av[r] * bb[q];
        }
        __syncthreads();
    }

#pragma unroll
    for (int r = 0; r < 4; ++r) {
        const int o = o0 + ty * 4 + r;
#pragma unroll
        for (int q = 0; q < 4; ++q) {
            const int n = n0 + tx * 4 + q;
            if (o < CQ) {
                fT[((size_t)b * NN + n) * CQ + o] = acc[r][q];
            } else if (o < 2 * CQ) {
                gT[((size_t)b * NN + n) * CQ + (o - CQ)] = acc[r][q];
            } else {
                hv[((size_t)b * CH + (o - 2 * CQ)) * NN + n] = f2bf(acc[r][q]);
            }
        }
    }
}

// ---------------------------------------------------------------------------
// Flash attention over i (softmax axis) for each output column j.
// One block = 16 j-columns of one batch; 256 threads; i-tile = 32.
// Output written as FP32 (reference output dtype).
// ---------------------------------------------------------------------------
__global__ __launch_bounds__(256) void attn_kernel(
    const void* __restrict__ xin, const float* __restrict__ fT,
    const float* __restrict__ gT, const u16* __restrict__ hv,
    const void* __restrict__ gammap, const int* __restrict__ flag,
    float* __restrict__ out)
{
    const int isbf = *flag;
    const int bid = blockIdx.x;          // 0..1023
    const int xcd = bid & 7, slot = bid >> 3;
    const int b  = xcd >> 1;                       // 2 XCDs per batch
    const int jb = ((xcd & 1) << 7) | slot;        // 0..255
    const int j0 = jb * 16;
    const int t  = threadIdx.x;
    const int jj = t & 15, ig = t >> 4;
    const int c0 = t * 2;

    __shared__ float Gt[16][68];   // g^T tile: Gt[j][k]
    __shared__ float Ft[32][68];   // f^T tile: Ft[i][k]
    __shared__ float Pl[16][36];   // P tile:  Pl[j][i]
    __shared__ float red[256];
    __shared__ float m_sto[16], l_sto[16], sc_lds[16];

    {   // load G tile once (gT is fp32)
        const int j = t >> 4, k = (t & 15) * 4;
        const float* p = gT + ((size_t)b * NN + j0 + j) * CQ + k;
        *(float4*)&Gt[j][k] = *(const float4*)p;
    }
    if (t < 16) { m_sto[t] = -3.0e38f; l_sto[t] = 0.f; }

    float acc0[16], acc1[16];
#pragma unroll
    for (int j = 0; j < 16; ++j) { acc0[j] = 0.f; acc1[j] = 0.f; }

    const u16* hp0 = hv + ((size_t)b * CH + c0) * NN;
    const u16* hp1 = hp0 + NN;

    __syncthreads();

    for (int it = 0; it < 128; ++it) {
        const int i0 = it * 32;
        {   // stage F tile [i][k] (fp32)
            const int i = t >> 3, k = (t & 7) * 8;
            const float* p = fT + ((size_t)b * NN + i0 + i) * CQ + k;
            *(float4*)&Ft[i][k]     = ((const float4*)p)[0];
            *(float4*)&Ft[i][k + 4] = ((const float4*)p)[1];
        }
        __syncthreads();

        // scores: S[i0+ig][j0+jj], S[i0+ig+16][j0+jj]
        float s0 = 0.f, s1 = 0.f;
#pragma unroll
        for (int kc = 0; kc < 64; kc += 4) {
            const float4 g4 = *(const float4*)&Gt[jj][kc];
            const float4 fa = *(const float4*)&Ft[ig][kc];
            const float4 fb = *(const float4*)&Ft[ig + 16][kc];
            s0 += fa.x * g4.x + fa.y * g4.y + fa.z * g4.z + fa.w * g4.w;
            s1 += fb.x * g4.x + fb.y * g4.y + fb.z * g4.z + fb.w * g4.w;
        }

        // per-j running max
        red[t] = fmaxf(s0, s1);
        __syncthreads();
        if (t < 16) {
            float mm = red[t];
#pragma unroll
            for (int u = 1; u < 16; ++u) mm = fmaxf(mm, red[t + 16 * u]);
            const float m_old = m_sto[t];
            const float m_new = fmaxf(m_old, mm);
            sc_lds[t] = __expf(m_old - m_new);
            m_sto[t]  = m_new;
        }
        __syncthreads();

        // P = exp(S - m), per-j partial sums
        const float m_new = m_sto[jj];
        const float p0 = __expf(s0 - m_new);
        const float p1 = __expf(s1 - m_new);
        Pl[jj][ig]      = p0;
        Pl[jj][ig + 16] = p1;
        red[t] = p0 + p1;
        __syncthreads();
        if (t < 16) {
            float ss = 0.f;
#pragma unroll
            for (int u = 0; u < 16; ++u) ss += red[t + 16 * u];
            l_sto[t] = l_sto[t] * sc_lds[t] + ss;
        }

        // rescale accumulators, then PV accumulate (2 channels x 16 j per thread)
#pragma unroll
        for (int j = 0; j < 16; ++j) {
            const float sc = sc_lds[j];
            acc0[j] *= sc; acc1[j] *= sc;
        }
#pragma unroll
        for (int ic = 0; ic < 4; ++ic) {
            const u16x8 a8 = *(const u16x8*)(hp0 + i0 + ic * 8);
            const u16x8 b8 = *(const u16x8*)(hp1 + i0 + ic * 8);
            float h0[8], h1[8];
#pragma unroll
            for (int e = 0; e < 8; ++e) { h0[e] = bf2f(a8[e]); h1[e] = bf2f(b8[e]); }
#pragma unroll
            for (int j = 0; j < 16; ++j) {
                const float4 pA = *(const float4*)&Pl[j][ic * 8];
                const float4 pB = *(const float4*)&Pl[j][ic * 8 + 4];
                acc0[j] += h0[0]*pA.x + h0[1]*pA.y + h0[2]*pA.z + h0[3]*pA.w
                         + h0[4]*pB.x + h0[5]*pB.y + h0[6]*pB.z + h0[7]*pB.w;
                acc1[j] += h1[0]*pA.x + h1[1]*pA.y + h1[2]*pA.z + h1[3]*pA.w
                         + h1[4]*pB.x + h1[5]*pB.y + h1[6]*pB.z + h1[7]*pB.w;
            }
        }
        // next-iteration staging barrier orders all shared-mem hazards
    }
    __syncthreads();

    // epilogue: out = gamma * acc / l + x   (FP32 output)
    float gam;
    if (isbf) gam = bf2f(((const u16*)gammap)[0]);
    else      gam = ((const float*)gammap)[0];

    const size_t xoff = ((size_t)b * CH + c0) * NN + j0;
    float* op = out + xoff;
#pragma unroll
    for (int j = 0; j < 16; ++j) {
        float xv0, xv1;
        if (isbf) {
            const u16* xp = (const u16*)xin + xoff;
            xv0 = bf2f(xp[j]); xv1 = bf2f(xp[NN + j]);
        } else {
            const float* xp = (const float*)xin + xoff;
            xv0 = xp[j]; xv1 = xp[NN + j];
        }
        const float inv = 1.0f / l_sto[j];
        op[j]      = gam * acc0[j] * inv + xv0;
        op[NN + j] = gam * acc1[j] * inv + xv1;
    }
}

extern "C" void kernel_launch(void* const* d_in, const int* in_sizes, int n_in,
                              void* d_out, int out_size, void* d_ws, size_t ws_size,
                              hipStream_t stream)
{
    // ws layout: [flag 256B][fT fp32 4MB][gT fp32 4MB][hv bf16 16MB] = 24.3 MB
    int*   flag = (int*)d_ws;
    float* fT = (float*)((char*)d_ws + 256);        // [B][N][CQ] fp32
    float* gT = fT + (size_t)BATCH * NN * CQ;       // [B][N][CQ] fp32
    u16*   hv = (u16*)(gT + (size_t)BATCH * NN * CQ); // [B][CH][N] bf16

    detect_kernel<<<1, 64, 0, stream>>>((const u32*)d_in[0], flag);

    dim3 pgrid(64, 10, BATCH);
    proj_kernel<<<pgrid, 256, 0, stream>>>(d_in[0], d_in[1], d_in[2], d_in[3],
                                           flag, fT, gT, hv);
    attn_kernel<<<1024, 256, 0, stream>>>(d_in[0], fT, gT, hv, d_in[4],
                                          flag, (float*)d_out);
}

// Round 4
// 422.084 us; speedup vs baseline: 4.2590x; 4.2590x over previous
//
#include <hip/hip_runtime.h>
#include <hip/hip_bf16.h>

typedef unsigned short u16;
typedef unsigned int   u32;
typedef _Float16 f16;
typedef __attribute__((ext_vector_type(8))) _Float16 f16x8;
typedef __attribute__((ext_vector_type(4))) _Float16 f16x4;
typedef __attribute__((ext_vector_type(4))) float    f32x4;
typedef __attribute__((ext_vector_type(8))) unsigned short u16x8;

#define BATCH 4
#define CH 512
#define NN 4096
#define CQ 64

__device__ __forceinline__ float bf2f(u16 v) {
    union { unsigned int u; float f; } x; x.u = ((unsigned int)v) << 16; return x.f;
}

// ---------------------------------------------------------------------------
// Input dtype detector (safety net): 0 = fp32 inputs, 1 = bf16 inputs.
// ---------------------------------------------------------------------------
__global__ __launch_bounds__(64) void detect_kernel(const u32* __restrict__ xw,
                                                    int* __restrict__ flag)
{
    const u32 w  = xw[threadIdx.x];
    const u32 ex = (w >> 23) & 0xFFu;
    const int plausible = (ex >= 100u && ex <= 132u) ? 1 : 0;
    const unsigned long long m = __ballot(plausible);
    if (threadIdx.x == 0) flag[0] = (__popcll(m) >= 48) ? 0 : 1;
}

// ---------------------------------------------------------------------------
// Projection GEMM (fp32 VALU, verified round 3): outputs now f16.
//   o <  64 : -> fT[b][n][o]      (f16, [N][CQ])
//   o < 128 : -> gT[b][n][o-64]   (f16, [N][CQ])
//   else    : -> hv[b][o-128][n]  (f16, [CH][N])
// ---------------------------------------------------------------------------
__global__ __launch_bounds__(256) void proj_kernel(
    const void* __restrict__ xin, const void* __restrict__ Wq,
    const void* __restrict__ Wk, const void* __restrict__ Wv,
    const int* __restrict__ flag,
    f16* __restrict__ fT, f16* __restrict__ gT, f16* __restrict__ hv)
{
    const int isbf = *flag;
    const int nb = blockIdx.x;
    const int rb = blockIdx.y;
    const int b  = blockIdx.z;
    const int n0 = nb * 64, o0 = rb * 64;
    const int t  = threadIdx.x;
    const int ty = t >> 4, tx = t & 15;

    __shared__ float Wl[64][68];
    __shared__ float Xl[64][68];

    float acc[4][4];
#pragma unroll
    for (int r = 0; r < 4; ++r)
#pragma unroll
        for (int q = 0; q < 4; ++q) acc[r][q] = 0.f;

    const int so = t >> 2;
    const int sk = (t & 3) * 16;

    const void* wsrc; int wrow;
    {
        const int go = o0 + so;
        if (go < 64)       { wsrc = Wq; wrow = go; }
        else if (go < 128) { wsrc = Wk; wrow = go - 64; }
        else               { wsrc = Wv; wrow = go - 128; }
    }

    for (int k0 = 0; k0 < CH; k0 += 64) {
        if (isbf) {
            {
                const u16* p = (const u16*)wsrc + (size_t)wrow * CH + k0 + sk;
                const u16x8 w0 = *(const u16x8*)p;
                const u16x8 w1 = *(const u16x8*)(p + 8);
#pragma unroll
                for (int e = 0; e < 8; ++e) Wl[sk + e][so] = bf2f(w0[e]);
#pragma unroll
                for (int e = 0; e < 8; ++e) Wl[sk + 8 + e][so] = bf2f(w1[e]);
            }
            {
                const u16* p = (const u16*)xin +
                               ((size_t)(b * CH + k0 + so)) * NN + n0 + sk;
                const u16x8 x0 = *(const u16x8*)p;
                const u16x8 x1 = *(const u16x8*)(p + 8);
                *(float4*)&Xl[so][sk] =
                    make_float4(bf2f(x0[0]), bf2f(x0[1]), bf2f(x0[2]), bf2f(x0[3]));
                *(float4*)&Xl[so][sk + 4] =
                    make_float4(bf2f(x0[4]), bf2f(x0[5]), bf2f(x0[6]), bf2f(x0[7]));
                *(float4*)&Xl[so][sk + 8] =
                    make_float4(bf2f(x1[0]), bf2f(x1[1]), bf2f(x1[2]), bf2f(x1[3]));
                *(float4*)&Xl[so][sk + 12] =
                    make_float4(bf2f(x1[4]), bf2f(x1[5]), bf2f(x1[6]), bf2f(x1[7]));
            }
        } else {
            {
                const float* p = (const float*)wsrc + (size_t)wrow * CH + k0 + sk;
                const float4 a0 = ((const float4*)p)[0];
                const float4 a1 = ((const float4*)p)[1];
                const float4 a2 = ((const float4*)p)[2];
                const float4 a3 = ((const float4*)p)[3];
                const float av[16] = {a0.x,a0.y,a0.z,a0.w, a1.x,a1.y,a1.z,a1.w,
                                      a2.x,a2.y,a2.z,a2.w, a3.x,a3.y,a3.z,a3.w};
#pragma unroll
                for (int e = 0; e < 16; ++e) Wl[sk + e][so] = av[e];
            }
            {
                const float* p = (const float*)xin +
                                 ((size_t)(b * CH + k0 + so)) * NN + n0 + sk;
                *(float4*)&Xl[so][sk]      = ((const float4*)p)[0];
                *(float4*)&Xl[so][sk + 4]  = ((const float4*)p)[1];
                *(float4*)&Xl[so][sk + 8]  = ((const float4*)p)[2];
                *(float4*)&Xl[so][sk + 12] = ((const float4*)p)[3];
            }
        }
        __syncthreads();
#pragma unroll 16
        for (int kk = 0; kk < 64; ++kk) {
            const float4 a  = *(const float4*)&Wl[kk][ty * 4];
            const float4 bv = *(const float4*)&Xl[kk][tx * 4];
            const float av[4] = {a.x, a.y, a.z, a.w};
            const float bb[4] = {bv.x, bv.y, bv.z, bv.w};
#pragma unroll
            for (int r = 0; r < 4; ++r)
#pragma unroll
                for (int q = 0; q < 4; ++q) acc[r][q] += av[r] * bb[q];
        }
        __syncthreads();
    }

#pragma unroll
    for (int r = 0; r < 4; ++r) {
        const int o = o0 + ty * 4 + r;
#pragma unroll
        for (int q = 0; q < 4; ++q) {
            const int n = n0 + tx * 4 + q;
            if (o < CQ) {
                fT[((size_t)b * NN + n) * CQ + o] = (f16)acc[r][q];
            } else if (o < 2 * CQ) {
                gT[((size_t)b * NN + n) * CQ + (o - CQ)] = (f16)acc[r][q];
            } else {
                hv[((size_t)b * CH + (o - 2 * CQ)) * NN + n] = (f16)acc[r][q];
            }
        }
    }
}

// ---------------------------------------------------------------------------
// MFMA flash attention. Block = 8 waves (512 thr), 32 j-columns; i-tile 256.
// S[i x j] via mfma(A=f, B=g): softmax over i = rows (in-lane + shfl).
// PV: O[c x j] via mfma(A=hv, B=P); wave w owns c in [64w, 64w+64).
// P staged in LDS, packed in B-fragment order, 16B-slot swizzle s^=(j&15).
// Fragment layouts (m97/m89-derived): A/B row|col = lane&15, k = 8*(lane>>4)+e
// (contiguous 8); C/D col = lane&15, row = 4*(lane>>4)+reg.
// ---------------------------------------------------------------------------
__global__ __launch_bounds__(512) void attn_mfma(
    const void* __restrict__ xin, const f16* __restrict__ fT,
    const f16* __restrict__ gT, const f16* __restrict__ hv,
    const void* __restrict__ gammap, const int* __restrict__ flag,
    float* __restrict__ out)
{
    const int isbf = *flag;
    const int bid  = blockIdx.x;                 // 0..511
    const int xcd  = bid & 7, slot = bid >> 3;   // slot 0..63
    const int b    = xcd >> 1;                   // 2 XCDs per batch
    const int jblk = ((xcd & 1) << 6) + slot;    // 0..127
    const int j0   = jblk * 32;
    const int t    = threadIdx.x;
    const int w    = t >> 6;                     // wave 0..7
    const int l    = t & 63;
    const int j16  = l & 15;
    const int h    = l >> 4;                     // 0..3

    __shared__ f16   Pp[32 * 256];               // 16 KB, swizzled pack of P
    __shared__ float wmax[8][2][16];
    __shared__ float wsum[8][2][16];

    // g B-fragments, resident whole kernel: [jb][kc]
    f16x8 gf[2][2];
#pragma unroll
    for (int jb = 0; jb < 2; ++jb)
#pragma unroll
        for (int kc = 0; kc < 2; ++kc)
            gf[jb][kc] = *(const f16x8*)(gT +
                ((size_t)b * NN + j0 + 16 * jb + j16) * CQ + 32 * kc + 8 * h);

    f32x4 oacc[4][2];                            // [cb][jb]
#pragma unroll
    for (int cb = 0; cb < 4; ++cb)
#pragma unroll
        for (int jb = 0; jb < 2; ++jb)
#pragma unroll
            for (int r = 0; r < 4; ++r) oacc[cb][jb][r] = 0.f;

    float m_run[2] = {-1e30f, -1e30f};
    float l_run[2] = {0.f, 0.f};

    const f16* fbase = fT + (size_t)b * NN * CQ;
    const f16* hbase = hv + (size_t)b * CH * NN;

    for (int it = 0; it < 16; ++it) {
        const int i0 = it * 256;

        // ---- QK^T: S[32 i x 32 j] for this wave's i-slice ----
        f32x4 s[2][2];
#pragma unroll
        for (int ib = 0; ib < 2; ++ib)
#pragma unroll
            for (int jb = 0; jb < 2; ++jb)
#pragma unroll
                for (int r = 0; r < 4; ++r) s[ib][jb][r] = 0.f;

#pragma unroll
        for (int ib = 0; ib < 2; ++ib) {
            const int irow = i0 + 32 * w + 16 * ib + j16;
            const f16x8 a0 = *(const f16x8*)(fbase + (size_t)irow * CQ + 8 * h);
            const f16x8 a1 = *(const f16x8*)(fbase + (size_t)irow * CQ + 32 + 8 * h);
#pragma unroll
            for (int jb = 0; jb < 2; ++jb) {
                s[ib][jb] = __builtin_amdgcn_mfma_f32_16x16x32_f16(
                                a0, gf[jb][0], s[ib][jb], 0, 0, 0);
                s[ib][jb] = __builtin_amdgcn_mfma_f32_16x16x32_f16(
                                a1, gf[jb][1], s[ib][jb], 0, 0, 0);
            }
        }

        // ---- per-column max (over rows = i) ----
        float pmax[2];
#pragma unroll
        for (int jb = 0; jb < 2; ++jb) {
            float m0 = fmaxf(fmaxf(s[0][jb][0], s[0][jb][1]),
                             fmaxf(s[0][jb][2], s[0][jb][3]));
            float m1 = fmaxf(fmaxf(s[1][jb][0], s[1][jb][1]),
                             fmaxf(s[1][jb][2], s[1][jb][3]));
            float mm = fmaxf(m0, m1);
            mm = fmaxf(mm, __shfl_xor(mm, 16));
            mm = fmaxf(mm, __shfl_xor(mm, 32));
            pmax[jb] = mm;
        }
        if (h == 0) { wmax[w][0][j16] = pmax[0]; wmax[w][1][j16] = pmax[1]; }
        __syncthreads();                          // barrier 1

        float m_new[2], sc[2];
#pragma unroll
        for (int jb = 0; jb < 2; ++jb) {
            float tm = wmax[0][jb][j16];
#pragma unroll
            for (int w2 = 1; w2 < 8; ++w2) tm = fmaxf(tm, wmax[w2][jb][j16]);
            m_new[jb] = fmaxf(m_run[jb], tm);
            sc[jb]    = __expf(m_run[jb] - m_new[jb]);
            m_run[jb] = m_new[jb];
        }

        // ---- P = exp(S - m): pack f16 into LDS + partial sums ----
        float psum[2] = {0.f, 0.f};
#pragma unroll
        for (int ib = 0; ib < 2; ++ib) {
#pragma unroll
            for (int jb = 0; jb < 2; ++jb) {
                const float p0 = __expf(s[ib][jb][0] - m_new[jb]);
                const float p1 = __expf(s[ib][jb][1] - m_new[jb]);
                const float p2 = __expf(s[ib][jb][2] - m_new[jb]);
                const float p3 = __expf(s[ib][jb][3] - m_new[jb]);
                psum[jb] += (p0 + p1) + (p2 + p3);
                f16x4 v4;
                v4[0] = (f16)p0; v4[1] = (f16)p1; v4[2] = (f16)p2; v4[3] = (f16)p3;
                const int jloc = 16 * jb + j16;
                const int sw   = (4 * w + 2 * ib + (h >> 1)) ^ j16;
                *(f16x4*)&Pp[jloc * 256 + sw * 8 + (h & 1) * 4] = v4;
            }
        }
#pragma unroll
        for (int jb = 0; jb < 2; ++jb) {
            psum[jb] += __shfl_xor(psum[jb], 16);
            psum[jb] += __shfl_xor(psum[jb], 32);
        }
        if (h == 0) { wsum[w][0][j16] = psum[0]; wsum[w][1][j16] = psum[1]; }

        // ---- rescale O by exp(m_old - m_new) ----
#pragma unroll
        for (int cb = 0; cb < 4; ++cb)
#pragma unroll
            for (int jb = 0; jb < 2; ++jb)
#pragma unroll
                for (int r = 0; r < 4; ++r) oacc[cb][jb][r] *= sc[jb];

        __syncthreads();                          // barrier 2 (P + sums ready)

#pragma unroll
        for (int jb = 0; jb < 2; ++jb) {
            float ts = 0.f;
#pragma unroll
            for (int w2 = 0; w2 < 8; ++w2) ts += wsum[w2][jb][j16];
            l_run[jb] = l_run[jb] * sc[jb] + ts;
        }

        // ---- PV: O[c x j] += hv[c, i-chunk] x P[i-chunk, j] ----
#pragma unroll 2
        for (int kc = 0; kc < 8; ++kc) {
            f16x8 pf[2];
#pragma unroll
            for (int jb = 0; jb < 2; ++jb) {
                const int jloc = 16 * jb + j16;
                const int sw   = (4 * kc + h) ^ j16;
                pf[jb] = *(const f16x8*)&Pp[jloc * 256 + sw * 8];
            }
#pragma unroll
            for (int cb = 0; cb < 4; ++cb) {
                const int crow = 64 * w + 16 * cb + j16;
                const f16x8 a = *(const f16x8*)(hbase +
                    (size_t)crow * NN + i0 + 32 * kc + 8 * h);
                oacc[cb][0] = __builtin_amdgcn_mfma_f32_16x16x32_f16(
                                  a, pf[0], oacc[cb][0], 0, 0, 0);
                oacc[cb][1] = __builtin_amdgcn_mfma_f32_16x16x32_f16(
                                  a, pf[1], oacc[cb][1], 0, 0, 0);
            }
        }
    }

    // ---- epilogue: out = gamma * O / l + x  (fp32 out) ----
    float gam;
    if (isbf) gam = bf2f(((const u16*)gammap)[0]);
    else      gam = ((const float*)gammap)[0];

    const float inv0 = gam / l_run[0];
    const float inv1 = gam / l_run[1];

#pragma unroll
    for (int cb = 0; cb < 4; ++cb) {
#pragma unroll
        for (int jb = 0; jb < 2; ++jb) {
            const float invj = jb ? inv1 : inv0;
            const int j = j0 + 16 * jb + j16;
#pragma unroll
            for (int r = 0; r < 4; ++r) {
                const int c = 64 * w + 16 * cb + 4 * h + r;
                const size_t idx = ((size_t)b * CH + c) * NN + j;
                float xv;
                if (isbf) xv = bf2f(((const u16*)xin)[idx]);
                else      xv = ((const float*)xin)[idx];
                out[idx] = oacc[cb][jb][r] * invj + xv;
            }
        }
    }
}

extern "C" void kernel_launch(void* const* d_in, const int* in_sizes, int n_in,
                              void* d_out, int out_size, void* d_ws, size_t ws_size,
                              hipStream_t stream)
{
    // ws layout: [flag 256B][fT f16 2MB][gT f16 2MB][hv f16 8MB]
    int* flag = (int*)d_ws;
    f16* fT = (f16*)((char*)d_ws + 256);            // [B][N][CQ]
    f16* gT = fT + (size_t)BATCH * NN * CQ;         // [B][N][CQ]
    f16* hv = gT + (size_t)BATCH * NN * CQ;         // [B][CH][N]

    detect_kernel<<<1, 64, 0, stream>>>((const u32*)d_in[0], flag);

    dim3 pgrid(64, 10, BATCH);
    proj_kernel<<<pgrid, 256, 0, stream>>>(d_in[0], d_in[1], d_in[2], d_in[3],
                                           flag, fT, gT, hv);
    attn_mfma<<<512, 512, 0, stream>>>(d_in[0], fT, gT, hv, d_in[4],
                                       flag, (float*)d_out);
}